// Round 1
// baseline (218.957 us; speedup 1.0000x reference)
//
#include <hip/hip_runtime.h>

typedef unsigned short u16;
typedef short bf16x8 __attribute__((ext_vector_type(8)));
typedef float f32x4 __attribute__((ext_vector_type(4)));
typedef u16 u16x8 __attribute__((ext_vector_type(8)));
typedef u16 u16x4 __attribute__((ext_vector_type(4)));

#define LQ   4096
#define EMB  512
#define NB   4
#define MROWS (NB * LQ)            // 16384
#define QSCALE 0.04419417382415922f // 1/sqrt(512)

__device__ __forceinline__ u16 f2bf(float f) {
  unsigned u = __builtin_bit_cast(unsigned, f);
  u += 0x7fffu + ((u >> 16) & 1u);
  return (u16)(u >> 16);
}
__device__ __forceinline__ float bf2f(u16 h) {
  unsigned u = ((unsigned)h) << 16;
  return __builtin_bit_cast(float, u);
}

// ---------------- prep: convert weights (+fold q-scale) and x to bf16 ----
__global__ void prep_w(const float* __restrict__ Wq, const float* __restrict__ bq,
                       const float* __restrict__ Wk, const float* __restrict__ bk,
                       const float* __restrict__ Wv, const float* __restrict__ bv,
                       u16* __restrict__ wqb, u16* __restrict__ wkb, u16* __restrict__ wvb,
                       float* __restrict__ bias) {
  int i = blockIdx.x * 256 + threadIdx.x;
  if (i < EMB * EMB) {
    wqb[i] = f2bf(Wq[i] * QSCALE);
    wkb[i] = f2bf(Wk[i]);
    wvb[i] = f2bf(Wv[i]);
  }
  if (i < EMB) {
    bias[i]           = bq[i] * QSCALE;
    bias[EMB + i]     = bk[i];
    bias[2 * EMB + i] = bv[i];
  }
}

__global__ void prep_x(const float* __restrict__ x, u16* __restrict__ xb) {
  int i = blockIdx.x * 256 + threadIdx.x;     // covers MROWS*EMB/8 threads
  const float4* p = (const float4*)(x + (size_t)i * 8);
  float4 a = p[0], b = p[1];
  u16x8 o;
  o[0] = f2bf(a.x); o[1] = f2bf(a.y); o[2] = f2bf(a.z); o[3] = f2bf(a.w);
  o[4] = f2bf(b.x); o[5] = f2bf(b.y); o[6] = f2bf(b.z); o[7] = f2bf(b.w);
  *(u16x8*)(xb + (size_t)i * 8) = o;
}

// ---------------- shared 128x128 GEMM core (A[M,K] * B[N,K]^T, bf16) -----
// 4 waves (256 thr), each wave 64x64 (4x4 frags of 16x16), BK=64.
// LDS tiles [128][64] bf16 with chunk XOR swizzle: conflict-free ds_read_b128.
__device__ __forceinline__ void gemm_tile_core(
    const u16* __restrict__ A, int lda,
    const u16* __restrict__ B, int ldb,
    int kIters, u16* ldsA, u16* ldsB,
    f32x4 acc[4][4], int tid, int lane, int wr, int wc)
{
  for (int kb = 0; kb < kIters; ++kb) {
    const u16* ga = A + kb * 64;
    const u16* gb = B + kb * 64;
#pragma unroll
    for (int p = 0; p < 4; ++p) {
      int c = tid + p * 256;         // chunk id 0..1023 (16B chunks)
      int row = c >> 3, h = c & 7;
      int hh = h ^ (row & 7);
      uint4 va = *(const uint4*)(ga + (size_t)row * lda + h * 8);
      uint4 vb = *(const uint4*)(gb + (size_t)row * ldb + h * 8);
      *(uint4*)(ldsA + row * 64 + hh * 8) = va;
      *(uint4*)(ldsB + row * 64 + hh * 8) = vb;
    }
    __syncthreads();
#pragma unroll
    for (int s = 0; s < 2; ++s) {
      bf16x8 af[4], bf[4];
#pragma unroll
      for (int m = 0; m < 4; ++m) {
        int row = wr * 64 + m * 16 + (lane & 15);
        int hh = (s * 4 + (lane >> 4)) ^ (row & 7);
        af[m] = *(const bf16x8*)(ldsA + row * 64 + hh * 8);
      }
#pragma unroll
      for (int n = 0; n < 4; ++n) {
        int row = wc * 64 + n * 16 + (lane & 15);
        int hh = (s * 4 + (lane >> 4)) ^ (row & 7);
        bf[n] = *(const bf16x8*)(ldsB + row * 64 + hh * 8);
      }
#pragma unroll
      for (int m = 0; m < 4; ++m)
#pragma unroll
        for (int n = 0; n < 4; ++n)
          acc[m][n] = __builtin_amdgcn_mfma_f32_16x16x32_bf16(af[m], bf[n], acc[m][n], 0, 0, 0);
    }
    __syncthreads();
  }
}

// ---------------- K1: QKV projection GEMM --------------------------------
// VT==0: out row-major bf16 [MROWS][512] (Q or K).  VT==1: out = Vt [NB][512][LQ].
template <int VT>
__global__ __launch_bounds__(256, 2) void k_qkv(
    const u16* __restrict__ xb, const u16* __restrict__ W,
    const float* __restrict__ bias, u16* __restrict__ out)
{
  __shared__ uint4 ldsraw[2048];
  u16* ldsA = (u16*)ldsraw;
  u16* ldsB = (u16*)(ldsraw + 1024);
  int bi = blockIdx.x;
  int rt = bi >> 2, ct = bi & 3;
  int tid = threadIdx.x, lane = tid & 63, wave = tid >> 6;
  int wr = wave >> 1, wc = wave & 1;
  f32x4 acc[4][4];
#pragma unroll
  for (int m = 0; m < 4; ++m)
#pragma unroll
    for (int n = 0; n < 4; ++n) acc[m][n] = (f32x4)0.0f;

  gemm_tile_core(xb + (size_t)rt * 128 * EMB, EMB,
                 W + (size_t)ct * 128 * EMB, EMB, EMB / 64,
                 ldsA, ldsB, acc, tid, lane, wr, wc);

#pragma unroll
  for (int m = 0; m < 4; ++m)
#pragma unroll
    for (int n = 0; n < 4; ++n) {
      int row0 = rt * 128 + wr * 64 + m * 16 + ((lane >> 4) << 2);
      int col  = ct * 128 + wc * 64 + n * 16 + (lane & 15);
      float bv = bias[col];
      if (VT == 0) {
#pragma unroll
        for (int r = 0; r < 4; ++r)
          out[(size_t)(row0 + r) * EMB + col] = f2bf(acc[m][n][r] + bv);
      } else {
        int b = row0 >> 12, l0 = row0 & (LQ - 1);
        u16x4 pk;
#pragma unroll
        for (int r = 0; r < 4; ++r) pk[r] = f2bf(acc[m][n][r] + bv);
        *(u16x4*)(out + ((size_t)(b * EMB + col)) * LQ + l0) = pk;
      }
    }
}

// ---------------- K2: S = Q K^T on causal (lower-tri) tiles --------------
__global__ __launch_bounds__(256, 2) void k_qk(
    const u16* __restrict__ Q, const u16* __restrict__ K,
    u16* __restrict__ S, int bstart)
{
  __shared__ uint4 ldsraw[2048];
  u16* ldsA = (u16*)ldsraw;
  u16* ldsB = (u16*)(ldsraw + 1024);
  int t = blockIdx.x;
  int b_local = t / 528;
  int i = t - b_local * 528;
  int qi = (int)((sqrtf(8.f * (float)i + 1.f) - 1.f) * 0.5f);
  while ((qi + 1) * (qi + 2) / 2 <= i) ++qi;
  while (qi * (qi + 1) / 2 > i) --qi;
  int ki = i - qi * (qi + 1) / 2;
  int bg = bstart + b_local;

  int tid = threadIdx.x, lane = tid & 63, wave = tid >> 6;
  int wr = wave >> 1, wc = wave & 1;
  f32x4 acc[4][4];
#pragma unroll
  for (int m = 0; m < 4; ++m)
#pragma unroll
    for (int n = 0; n < 4; ++n) acc[m][n] = (f32x4)0.0f;

  gemm_tile_core(Q + ((size_t)bg * LQ + qi * 128) * EMB, EMB,
                 K + ((size_t)bg * LQ + ki * 128) * EMB, EMB, EMB / 64,
                 ldsA, ldsB, acc, tid, lane, wr, wc);

  u16* Sb = S + (size_t)b_local * LQ * LQ;
#pragma unroll
  for (int m = 0; m < 4; ++m)
#pragma unroll
    for (int n = 0; n < 4; ++n) {
      int row0 = qi * 128 + wr * 64 + m * 16 + ((lane >> 4) << 2);
      int col  = ki * 128 + wc * 64 + n * 16 + (lane & 15);
#pragma unroll
      for (int r = 0; r < 4; ++r) {
        int row = row0 + r;
        float v = (col > row) ? -1e9f : acc[m][n][r];
        Sb[(size_t)row * LQ + col] = f2bf(v);
      }
    }
}

// ---------------- K3: per-row softmax, in place (bf16) -------------------
__global__ __launch_bounds__(256) void k_softmax(u16* __restrict__ S)
{
  int rowb = blockIdx.x;               // b_local*LQ + q
  int q = rowb & (LQ - 1);
  u16* sr = S + (size_t)rowb * LQ;
  int n = ((q >> 7) + 1) << 7;         // valid extent (to end of diagonal tile)
  int tid = threadIdx.x;
  int lane = tid & 63, wave = tid >> 6;
  __shared__ float red[8];

  float v[16];
  float mx = -3.0e38f;
#pragma unroll
  for (int p = 0; p < 2; ++p) {
    int idx = (p * 256 + tid) * 8;
    if (idx < n) {
      u16x8 raw = *(const u16x8*)(sr + idx);
#pragma unroll
      for (int j = 0; j < 8; ++j) {
        float f = bf2f(raw[j]);
        v[p * 8 + j] = f;
        mx = fmaxf(mx, f);
      }
    }
  }
#pragma unroll
  for (int off = 32; off >= 1; off >>= 1) mx = fmaxf(mx, __shfl_xor(mx, off));
  if (lane == 0) red[wave] = mx;
  __syncthreads();
  if (tid == 0) red[4] = fmaxf(fmaxf(red[0], red[1]), fmaxf(red[2], red[3]));
  __syncthreads();
  mx = red[4];
  __syncthreads();

  float sum = 0.f;
#pragma unroll
  for (int p = 0; p < 2; ++p) {
    int idx = (p * 256 + tid) * 8;
    if (idx < n) {
#pragma unroll
      for (int j = 0; j < 8; ++j) {
        float e = __expf(v[p * 8 + j] - mx);
        v[p * 8 + j] = e;
        sum += e;
      }
    }
  }
#pragma unroll
  for (int off = 32; off >= 1; off >>= 1) sum += __shfl_xor(sum, off);
  if (lane == 0) red[wave] = sum;
  __syncthreads();
  if (tid == 0) red[4] = red[0] + red[1] + red[2] + red[3];
  __syncthreads();
  float inv = 1.0f / red[4];

#pragma unroll
  for (int p = 0; p < 2; ++p) {
    int idx = (p * 256 + tid) * 8;
    if (idx < n) {
      u16x8 o;
#pragma unroll
      for (int j = 0; j < 8; ++j) o[j] = f2bf(v[p * 8 + j] * inv);
      *(u16x8*)(sr + idx) = o;
    }
  }
}

// ---------------- K4: out = P @ V (via Vt), fp32 out ---------------------
__global__ __launch_bounds__(256, 2) void k_pv(
    const u16* __restrict__ P, const u16* __restrict__ Vt,
    float* __restrict__ out, int bstart, int bcount)
{
  __shared__ uint4 ldsraw[2048];
  u16* ldsA = (u16*)ldsraw;
  u16* ldsB = (u16*)(ldsraw + 1024);
  int bi = blockIdx.x;
  int per_rt = bcount * 4;
  int rt = 31 - bi / per_rt;           // descending cost order
  int rem = bi % per_rt;
  int b_local = rem >> 2, ct = rem & 3;
  int bg = bstart + b_local;

  int tid = threadIdx.x, lane = tid & 63, wave = tid >> 6;
  int wr = wave >> 1, wc = wave & 1;
  f32x4 acc[4][4];
#pragma unroll
  for (int m = 0; m < 4; ++m)
#pragma unroll
    for (int n = 0; n < 4; ++n) acc[m][n] = (f32x4)0.0f;

  int kIters = (rt + 1) * 2;           // span = (rt+1)*128
  gemm_tile_core(P + (size_t)b_local * LQ * LQ + (size_t)rt * 128 * LQ, LQ,
                 Vt + ((size_t)bg * EMB + ct * 128) * LQ, LQ, kIters,
                 ldsA, ldsB, acc, tid, lane, wr, wc);

#pragma unroll
  for (int m = 0; m < 4; ++m)
#pragma unroll
    for (int n = 0; n < 4; ++n) {
      int row0 = rt * 128 + wr * 64 + m * 16 + ((lane >> 4) << 2);
      int col  = ct * 128 + wc * 64 + n * 16 + (lane & 15);
#pragma unroll
      for (int r = 0; r < 4; ++r)
        out[((size_t)bg * LQ + row0 + r) * EMB + col] = acc[m][n][r];
    }
}

// ---------------- host ----------------------------------------------------
extern "C" void kernel_launch(void* const* d_in, const int* in_sizes, int n_in,
                              void* d_out, int out_size, void* d_ws, size_t ws_size,
                              hipStream_t stream) {
  const float* x  = (const float*)d_in[0];
  const float* Wq = (const float*)d_in[1];
  const float* bq = (const float*)d_in[2];
  const float* Wk = (const float*)d_in[3];
  const float* bk = (const float*)d_in[4];
  const float* Wv = (const float*)d_in[5];
  const float* bv = (const float*)d_in[6];

  char* ws = (char*)d_ws;
  size_t off = 0;
  u16* xb  = (u16*)(ws + off); off += (size_t)MROWS * EMB * 2;        // 16 MB
  u16* wqb = (u16*)(ws + off); off += (size_t)EMB * EMB * 2;
  u16* wkb = (u16*)(ws + off); off += (size_t)EMB * EMB * 2;
  u16* wvb = (u16*)(ws + off); off += (size_t)EMB * EMB * 2;
  float* bias = (float*)(ws + off); off += 3 * EMB * 4;
  off = (off + 255) & ~(size_t)255;
  u16* Qb  = (u16*)(ws + off); off += (size_t)MROWS * EMB * 2;
  u16* Kb  = (u16*)(ws + off); off += (size_t)MROWS * EMB * 2;
  u16* Vtb = (u16*)(ws + off); off += (size_t)MROWS * EMB * 2;
  size_t fixed = off;
  size_t s_full = (size_t)NB * LQ * LQ * 2;                            // 128 MB
  int bcap = (ws_size >= fixed + s_full) ? NB : 1;
  u16* Sb = (u16*)(ws + fixed);

  prep_w<<<(EMB * EMB + 255) / 256, 256, 0, stream>>>(Wq, bq, Wk, bk, Wv, bv,
                                                      wqb, wkb, wvb, bias);
  prep_x<<<(MROWS * EMB / 8) / 256, 256, 0, stream>>>(x, xb);

  k_qkv<0><<<512, 256, 0, stream>>>(xb, wqb, bias, Qb);
  k_qkv<0><<<512, 256, 0, stream>>>(xb, wkb, bias + EMB, Kb);
  k_qkv<1><<<512, 256, 0, stream>>>(xb, wvb, bias + 2 * EMB, Vtb);

  for (int bs = 0; bs < NB; bs += bcap) {
    int bc = (bs + bcap <= NB) ? bcap : (NB - bs);
    k_qk<<<528 * bc, 256, 0, stream>>>(Qb, Kb, Sb, bs);
    k_softmax<<<bc * LQ, 256, 0, stream>>>(Sb);
    k_pv<<<32 * bc * 4, 256, 0, stream>>>(Sb, Vtb, (float*)d_out, bs, bc);
  }
}

// Round 2
// 211.878 us; speedup vs baseline: 1.0334x; 1.0334x over previous
//
#include <hip/hip_runtime.h>

typedef unsigned short u16;
typedef unsigned int u32;
typedef short bf16x8 __attribute__((ext_vector_type(8)));
typedef float f32x4 __attribute__((ext_vector_type(4)));
typedef u16 u16x8 __attribute__((ext_vector_type(8)));
typedef u16 u16x4 __attribute__((ext_vector_type(4)));

typedef const __attribute__((address_space(1))) u32* gas_ptr;
typedef __attribute__((address_space(3))) u32* las_ptr;

#define LQ   4096
#define EMB  512
#define NB   4
#define MROWS (NB * LQ)            // 16384
#define QSCALE 0.04419417382415922f // 1/sqrt(512)

__device__ __forceinline__ u16 f2bf(float f) {
  unsigned u = __builtin_bit_cast(unsigned, f);
  u += 0x7fffu + ((u >> 16) & 1u);
  return (u16)(u >> 16);
}
__device__ __forceinline__ float bf2f(u16 h) {
  unsigned u = ((unsigned)h) << 16;
  return __builtin_bit_cast(float, u);
}

// ---------------- prep: convert weights (+fold q-scale) and x to bf16 ----
__global__ void prep_w(const float* __restrict__ Wq, const float* __restrict__ bq,
                       const float* __restrict__ Wk, const float* __restrict__ bk,
                       const float* __restrict__ Wv, const float* __restrict__ bv,
                       u16* __restrict__ wqb, u16* __restrict__ wkb, u16* __restrict__ wvb,
                       float* __restrict__ bias) {
  int i = blockIdx.x * 256 + threadIdx.x;
  if (i < EMB * EMB) {
    wqb[i] = f2bf(Wq[i] * QSCALE);
    wkb[i] = f2bf(Wk[i]);
    wvb[i] = f2bf(Wv[i]);
  }
  if (i < EMB) {
    bias[i]           = bq[i] * QSCALE;
    bias[EMB + i]     = bk[i];
    bias[2 * EMB + i] = bv[i];
  }
}

__global__ void prep_x(const float* __restrict__ x, u16* __restrict__ xb) {
  int i = blockIdx.x * 256 + threadIdx.x;     // covers MROWS*EMB/8 threads
  const float4* p = (const float4*)(x + (size_t)i * 8);
  float4 a = p[0], b = p[1];
  u16x8 o;
  o[0] = f2bf(a.x); o[1] = f2bf(a.y); o[2] = f2bf(a.z); o[3] = f2bf(a.w);
  o[4] = f2bf(b.x); o[5] = f2bf(b.y); o[6] = f2bf(b.z); o[7] = f2bf(b.w);
  *(u16x8*)(xb + (size_t)i * 8) = o;
}

// ---------------- shared 128x128 GEMM core (A[M,K] * B[N,K]^T, bf16) -----
// 4 waves (256 thr), each wave 64x64 (4x4 frags of 16x16), BK=64.
// Staging: global_load_lds width=16, LINEAR LDS dest, inverse-XOR-swizzled
// global source (rule #21).  ds_read side applies the same XOR -> conflict-free
// ds_read_b128.
__device__ __forceinline__ void gemm_tile_core(
    const u16* __restrict__ A, int lda,
    const u16* __restrict__ B, int ldb,
    int kIters, u16* ldsA, u16* ldsB,
    f32x4 acc[4][4], int tid, int lane, int wr, int wc)
{
  int wave = tid >> 6;
  for (int kb = 0; kb < kIters; ++kb) {
    const u16* ga = A + kb * 64;
    const u16* gb = B + kb * 64;
#pragma unroll
    for (int p = 0; p < 4; ++p) {
      int c = tid + p * 256;         // linear LDS chunk id 0..1023 (16B chunks)
      int row = c >> 3, hh = c & 7;
      int h = hh ^ (row & 7);        // inverse swizzle on the global side
      const u16* sa = ga + (size_t)row * lda + h * 8;
      const u16* sb = gb + (size_t)row * ldb + h * 8;
      u16* la = ldsA + wave * 512 + p * 2048;   // wave-uniform base (bytes: wave*1024+p*4096)
      u16* lb = ldsB + wave * 512 + p * 2048;
      __builtin_amdgcn_global_load_lds((gas_ptr)(const void*)sa, (las_ptr)(void*)la, 16, 0, 0);
      __builtin_amdgcn_global_load_lds((gas_ptr)(const void*)sb, (las_ptr)(void*)lb, 16, 0, 0);
    }
    __syncthreads();
#pragma unroll
    for (int s = 0; s < 2; ++s) {
      bf16x8 af[4], bfr[4];
#pragma unroll
      for (int m = 0; m < 4; ++m) {
        int row = wr * 64 + m * 16 + (lane & 15);
        int hh = (s * 4 + (lane >> 4)) ^ (row & 7);
        af[m] = *(const bf16x8*)(ldsA + row * 64 + hh * 8);
      }
#pragma unroll
      for (int n = 0; n < 4; ++n) {
        int row = wc * 64 + n * 16 + (lane & 15);
        int hh = (s * 4 + (lane >> 4)) ^ (row & 7);
        bfr[n] = *(const bf16x8*)(ldsB + row * 64 + hh * 8);
      }
#pragma unroll
      for (int m = 0; m < 4; ++m)
#pragma unroll
        for (int n = 0; n < 4; ++n)
          acc[m][n] = __builtin_amdgcn_mfma_f32_16x16x32_bf16(af[m], bfr[n], acc[m][n], 0, 0, 0);
    }
    __syncthreads();
  }
}

// ---------------- K1: fused QKV projection GEMM --------------------------
// which = bi/512: 0->Q (row-major), 1->K (row-major), 2->V (transposed Vt).
__global__ __launch_bounds__(256, 2) void k_qkv(
    const u16* __restrict__ xb,
    const u16* __restrict__ w0, const u16* __restrict__ w1, const u16* __restrict__ w2,
    const float* __restrict__ bias,
    u16* __restrict__ o0, u16* __restrict__ o1, u16* __restrict__ o2)
{
  __shared__ uint4 ldsraw[2048];
  u16* ldsA = (u16*)ldsraw;
  u16* ldsB = (u16*)(ldsraw + 1024);
  int bi = blockIdx.x;
  int which = bi >> 9;
  int t = bi & 511;
  int rt = t >> 2, ct = t & 3;
  const u16* W = (which == 0) ? w0 : (which == 1) ? w1 : w2;
  const float* bs = bias + which * EMB;
  int tid = threadIdx.x, lane = tid & 63, wave = tid >> 6;
  int wr = wave >> 1, wc = wave & 1;
  f32x4 acc[4][4];
#pragma unroll
  for (int m = 0; m < 4; ++m)
#pragma unroll
    for (int n = 0; n < 4; ++n) acc[m][n] = (f32x4)0.0f;

  gemm_tile_core(xb + (size_t)rt * 128 * EMB, EMB,
                 W + (size_t)ct * 128 * EMB, EMB, EMB / 64,
                 ldsA, ldsB, acc, tid, lane, wr, wc);

#pragma unroll
  for (int m = 0; m < 4; ++m)
#pragma unroll
    for (int n = 0; n < 4; ++n) {
      int row0 = rt * 128 + wr * 64 + m * 16 + ((lane >> 4) << 2);
      int col  = ct * 128 + wc * 64 + n * 16 + (lane & 15);
      float bv = bs[col];
      if (which < 2) {
        u16* out = (which == 0) ? o0 : o1;
#pragma unroll
        for (int r = 0; r < 4; ++r)
          out[(size_t)(row0 + r) * EMB + col] = f2bf(acc[m][n][r] + bv);
      } else {
        int b = row0 >> 12, l0 = row0 & (LQ - 1);
        u16x4 pk;
#pragma unroll
        for (int r = 0; r < 4; ++r) pk[r] = f2bf(acc[m][n][r] + bv);
        *(u16x4*)(o2 + ((size_t)(b * EMB + col)) * LQ + l0) = pk;
      }
    }
}

// ---------------- K2: S = Q K^T on causal (lower-tri) tiles --------------
__global__ __launch_bounds__(256, 2) void k_qk(
    const u16* __restrict__ Q, const u16* __restrict__ K,
    u16* __restrict__ S, int bstart)
{
  __shared__ uint4 ldsraw[2048];
  u16* ldsA = (u16*)ldsraw;
  u16* ldsB = (u16*)(ldsraw + 1024);
  int t = blockIdx.x;
  int b_local = t / 528;
  int i = t - b_local * 528;
  int qi = (int)((sqrtf(8.f * (float)i + 1.f) - 1.f) * 0.5f);
  while ((qi + 1) * (qi + 2) / 2 <= i) ++qi;
  while (qi * (qi + 1) / 2 > i) --qi;
  int ki = i - qi * (qi + 1) / 2;
  int bg = bstart + b_local;

  int tid = threadIdx.x, lane = tid & 63, wave = tid >> 6;
  int wr = wave >> 1, wc = wave & 1;
  f32x4 acc[4][4];
#pragma unroll
  for (int m = 0; m < 4; ++m)
#pragma unroll
    for (int n = 0; n < 4; ++n) acc[m][n] = (f32x4)0.0f;

  gemm_tile_core(Q + ((size_t)bg * LQ + qi * 128) * EMB, EMB,
                 K + ((size_t)bg * LQ + ki * 128) * EMB, EMB, EMB / 64,
                 ldsA, ldsB, acc, tid, lane, wr, wc);

  u16* Sb = S + (size_t)b_local * LQ * LQ;
#pragma unroll
  for (int m = 0; m < 4; ++m)
#pragma unroll
    for (int n = 0; n < 4; ++n) {
      int row0 = qi * 128 + wr * 64 + m * 16 + ((lane >> 4) << 2);
      int col  = ki * 128 + wc * 64 + n * 16 + (lane & 15);
#pragma unroll
      for (int r = 0; r < 4; ++r) {
        int row = row0 + r;
        float v = (col > row) ? -1e9f : acc[m][n][r];
        Sb[(size_t)row * LQ + col] = f2bf(v);
      }
    }
}

// ---------------- K3: per-row softmax, in place (bf16) -------------------
__global__ __launch_bounds__(256) void k_softmax(u16* __restrict__ S)
{
  int rowb = blockIdx.x;               // b_local*LQ + q
  int q = rowb & (LQ - 1);
  u16* sr = S + (size_t)rowb * LQ;
  int n = ((q >> 7) + 1) << 7;         // valid extent (to end of diagonal tile)
  int tid = threadIdx.x;
  int lane = tid & 63, wave = tid >> 6;
  __shared__ float red[8];

  float v[16];
  float mx = -3.0e38f;
#pragma unroll
  for (int p = 0; p < 2; ++p) {
    int idx = (p * 256 + tid) * 8;
    if (idx < n) {
      u16x8 raw = *(const u16x8*)(sr + idx);
#pragma unroll
      for (int j = 0; j < 8; ++j) {
        float f = bf2f(raw[j]);
        v[p * 8 + j] = f;
        mx = fmaxf(mx, f);
      }
    }
  }
#pragma unroll
  for (int off = 32; off >= 1; off >>= 1) mx = fmaxf(mx, __shfl_xor(mx, off));
  if (lane == 0) red[wave] = mx;
  __syncthreads();
  if (tid == 0) red[4] = fmaxf(fmaxf(red[0], red[1]), fmaxf(red[2], red[3]));
  __syncthreads();
  mx = red[4];
  __syncthreads();

  float sum = 0.f;
#pragma unroll
  for (int p = 0; p < 2; ++p) {
    int idx = (p * 256 + tid) * 8;
    if (idx < n) {
#pragma unroll
      for (int j = 0; j < 8; ++j) {
        float e = __expf(v[p * 8 + j] - mx);
        v[p * 8 + j] = e;
        sum += e;
      }
    }
  }
#pragma unroll
  for (int off = 32; off >= 1; off >>= 1) sum += __shfl_xor(sum, off);
  if (lane == 0) red[wave] = sum;
  __syncthreads();
  if (tid == 0) red[4] = red[0] + red[1] + red[2] + red[3];
  __syncthreads();
  float inv = 1.0f / red[4];

#pragma unroll
  for (int p = 0; p < 2; ++p) {
    int idx = (p * 256 + tid) * 8;
    if (idx < n) {
      u16x8 o;
#pragma unroll
      for (int j = 0; j < 8; ++j) o[j] = f2bf(v[p * 8 + j] * inv);
      *(u16x8*)(sr + idx) = o;
    }
  }
}

// ---------------- K4: out = P @ V (via Vt), fp32 out ---------------------
// rt assignment: antidiagonal-paired so co-scheduled block pairs (bi, bi+G/2)
// have uniform combined work (33 kIters) -> load balance across CUs.
__global__ __launch_bounds__(256, 2) void k_pv(
    const u16* __restrict__ P, const u16* __restrict__ Vt,
    float* __restrict__ out, int bstart, int bcount)
{
  __shared__ uint4 ldsraw[2048];
  u16* ldsA = (u16*)ldsraw;
  u16* ldsB = (u16*)(ldsraw + 1024);
  int bi = blockIdx.x;
  int per_rt = bcount * 4;
  int idx = bi / per_rt;               // 0..31
  int rem = bi % per_rt;
  int rt = (idx < 16) ? (31 - idx) : (idx - 16);
  int b_local = rem >> 2, ct = rem & 3;
  int bg = bstart + b_local;

  int tid = threadIdx.x, lane = tid & 63, wave = tid >> 6;
  int wr = wave >> 1, wc = wave & 1;
  f32x4 acc[4][4];
#pragma unroll
  for (int m = 0; m < 4; ++m)
#pragma unroll
    for (int n = 0; n < 4; ++n) acc[m][n] = (f32x4)0.0f;

  int kIters = (rt + 1) * 2;           // span = (rt+1)*128
  gemm_tile_core(P + (size_t)b_local * LQ * LQ + (size_t)rt * 128 * LQ, LQ,
                 Vt + ((size_t)bg * EMB + ct * 128) * LQ, LQ, kIters,
                 ldsA, ldsB, acc, tid, lane, wr, wc);

#pragma unroll
  for (int m = 0; m < 4; ++m)
#pragma unroll
    for (int n = 0; n < 4; ++n) {
      int row0 = rt * 128 + wr * 64 + m * 16 + ((lane >> 4) << 2);
      int col  = ct * 128 + wc * 64 + n * 16 + (lane & 15);
#pragma unroll
      for (int r = 0; r < 4; ++r)
        out[((size_t)bg * LQ + row0 + r) * EMB + col] = acc[m][n][r];
    }
}

// ---------------- host ----------------------------------------------------
extern "C" void kernel_launch(void* const* d_in, const int* in_sizes, int n_in,
                              void* d_out, int out_size, void* d_ws, size_t ws_size,
                              hipStream_t stream) {
  const float* x  = (const float*)d_in[0];
  const float* Wq = (const float*)d_in[1];
  const float* bq = (const float*)d_in[2];
  const float* Wk = (const float*)d_in[3];
  const float* bk = (const float*)d_in[4];
  const float* Wv = (const float*)d_in[5];
  const float* bv = (const float*)d_in[6];

  char* ws = (char*)d_ws;
  size_t off = 0;
  u16* xb  = (u16*)(ws + off); off += (size_t)MROWS * EMB * 2;        // 16 MB
  u16* wqb = (u16*)(ws + off); off += (size_t)EMB * EMB * 2;
  u16* wkb = (u16*)(ws + off); off += (size_t)EMB * EMB * 2;
  u16* wvb = (u16*)(ws + off); off += (size_t)EMB * EMB * 2;
  float* bias = (float*)(ws + off); off += 3 * EMB * 4;
  off = (off + 255) & ~(size_t)255;
  u16* Qb  = (u16*)(ws + off); off += (size_t)MROWS * EMB * 2;
  u16* Kb  = (u16*)(ws + off); off += (size_t)MROWS * EMB * 2;
  u16* Vtb = (u16*)(ws + off); off += (size_t)MROWS * EMB * 2;
  size_t fixed = off;
  size_t s_full = (size_t)NB * LQ * LQ * 2;                            // 128 MB
  int bcap = (ws_size >= fixed + s_full) ? NB : 1;
  u16* Sb = (u16*)(ws + fixed);

  prep_w<<<(EMB * EMB + 255) / 256, 256, 0, stream>>>(Wq, bq, Wk, bk, Wv, bv,
                                                      wqb, wkb, wvb, bias);
  prep_x<<<(MROWS * EMB / 8) / 256, 256, 0, stream>>>(x, xb);

  k_qkv<<<1536, 256, 0, stream>>>(xb, wqb, wkb, wvb, bias, Qb, Kb, Vtb);

  for (int bs = 0; bs < NB; bs += bcap) {
    int bc = (bs + bcap <= NB) ? bcap : (NB - bs);
    k_qk<<<528 * bc, 256, 0, stream>>>(Qb, Kb, Sb, bs);
    k_softmax<<<bc * LQ, 256, 0, stream>>>(Sb);
    k_pv<<<32 * bc * 4, 256, 0, stream>>>(Sb, Vtb, (float*)d_out, bs, bc);
  }
}